// Round 1
// baseline (956.962 us; speedup 1.0000x reference)
//
#include <hip/hip_runtime.h>
#include <math.h>

// Problem constants (B=4, L=2048 -> N=8192 tokens)
#define NTOK 8192
#define DDIM 512
#define HDIM 1024
#define NEXP 8
#define TOPK 2

// ---------------- workspace layout (bytes) ----------------
// 0     : int   counts[NEXP]        (doubles as freqs)
// 32    : float psum[NEXP]
// 64    : float zl_sum
// 128   : float gates[NTOK*TOPK]    (renormalized top-k gate values, slot n*2+k)
// 65664 : int   list[NEXP*NTOK]     (per-expert slot lists, entry = n*2+k)
// 327808: float hbuf[NTOK*TOPK*HDIM] (relu'd hidden activations per slot)
// total needed ~= 67.4 MB
#define WS_PSUM_OFF   32
#define WS_ZL_OFF     64
#define WS_GATES_OFF  128
#define WS_LIST_OFF   (WS_GATES_OFF + NTOK * TOPK * 4)
#define WS_HBUF_OFF   (WS_LIST_OFF + NEXP * NTOK * 4)

// ---------------------------------------------------------------------------
// Gating: one wave per token. logits = x[n] . w_gate[e], softmax over E=8,
// top-2 (ties -> lowest index, matching jax.lax.top_k), renormalize by
// (g0+g1+1e-6). Builds per-expert lists + loss partial sums.
// ---------------------------------------------------------------------------
__global__ __launch_bounds__(256)
void gate_kernel(const float* __restrict__ x, const float* __restrict__ wg,
                 int* __restrict__ counts, float* __restrict__ psum,
                 float* __restrict__ zl_sum, float* __restrict__ gates,
                 int* __restrict__ list) {
    __shared__ float wls[NEXP * DDIM];   // 16 KB
    __shared__ float blk_psum[NEXP];
    __shared__ float blk_zl;
    const int t = threadIdx.x;

    for (int i = t; i < NEXP * DDIM / 4; i += 256)
        ((float4*)wls)[i] = ((const float4*)wg)[i];
    if (t < NEXP) blk_psum[t] = 0.f;
    if (t == 0) blk_zl = 0.f;
    __syncthreads();

    const int wave = t >> 6, lane = t & 63;
    const int n = blockIdx.x * 4 + wave;

    float acc[NEXP];
#pragma unroll
    for (int e = 0; e < NEXP; ++e) acc[e] = 0.f;
    const float* xr = x + (size_t)n * DDIM;
#pragma unroll
    for (int it = 0; it < DDIM / 64; ++it) {
        const float xv = xr[lane + 64 * it];
#pragma unroll
        for (int e = 0; e < NEXP; ++e)
            acc[e] = fmaf(xv, wls[e * DDIM + lane + 64 * it], acc[e]);
    }
    // butterfly reduce across the 64-lane wave; all lanes end with full sums
#pragma unroll
    for (int e = 0; e < NEXP; ++e) {
#pragma unroll
        for (int off = 32; off > 0; off >>= 1)
            acc[e] += __shfl_xor(acc[e], off);
    }

    // softmax (redundantly on all lanes; only lane 0 writes)
    float m = acc[0];
#pragma unroll
    for (int e = 1; e < NEXP; ++e) m = fmaxf(m, acc[e]);
    float p[NEXP];
    float se = 0.f;
#pragma unroll
    for (int e = 0; e < NEXP; ++e) { p[e] = expf(acc[e] - m); se += p[e]; }
    const float lse = m + logf(se);
    const float inv = 1.f / se;
#pragma unroll
    for (int e = 0; e < NEXP; ++e) p[e] *= inv;

    // top-2, strict > keeps lowest index on ties (jax.lax.top_k semantics)
    int e0 = 0; float g0 = p[0];
#pragma unroll
    for (int e = 1; e < NEXP; ++e) if (p[e] > g0) { g0 = p[e]; e0 = e; }
    int e1 = -1; float g1 = -1.f;
#pragma unroll
    for (int e = 0; e < NEXP; ++e) if (e != e0 && p[e] > g1) { g1 = p[e]; e1 = e; }
    const float denom = g0 + g1 + 1e-6f;

    if (lane == 0) {
        gates[n * 2 + 0] = g0 / denom;
        gates[n * 2 + 1] = g1 / denom;
        const int p0 = atomicAdd(&counts[e0], 1);
        list[e0 * NTOK + p0] = n * 2 + 0;
        const int p1 = atomicAdd(&counts[e1], 1);
        list[e1 * NTOK + p1] = n * 2 + 1;
#pragma unroll
        for (int e = 0; e < NEXP; ++e) atomicAdd(&blk_psum[e], p[e]);
        atomicAdd(&blk_zl, lse * lse);
    }
    __syncthreads();
    if (t < NEXP) atomicAdd(&psum[t], blk_psum[t]);
    if (t == 0) atomicAdd(zl_sum, blk_zl);
}

// ---------------------------------------------------------------------------
// Per-expert gathered GEMM, 128x128 tile, BK=16, 8x8 micro-tile, 256 threads.
// PASS2=false: h[slot] = relu(x[n] @ w1[e] + b1[e])   (KD=512,  ND=1024)
// PASS2=true : y[n]   += gate * (h[slot] @ w2[e] + b2[e])  via atomicAdd
//                                                     (KD=1024, ND=512)
// Grid: (ND/128, NTOK/128, NEXP); blocks past counts[e] exit early.
// ---------------------------------------------------------------------------
template <int KD, int ND, bool PASS2>
__global__ __launch_bounds__(256)
void ffn_gemm(const float* __restrict__ A_src, const float* __restrict__ W,
              const float* __restrict__ bias, const int* __restrict__ counts,
              const int* __restrict__ list, const float* __restrict__ gates,
              float* __restrict__ outp) {
    const int e = blockIdx.z;
    const int cnt = counts[e];
    const int row0 = blockIdx.y * 128;
    if (row0 >= cnt) return;
    const int col0 = blockIdx.x * 128;

    __shared__ float As[16 * 132];   // A stored transposed [k][m], stride 132 (16B-aligned rows, conflict-light)
    __shared__ float Bs[16 * 128];
    __shared__ int   ls_entry[128];
    __shared__ float ls_gate[128];

    const int t = threadIdx.x;
    if (t < 128) {
        const int r = row0 + t;
        const int entry = (r < cnt) ? list[e * NTOK + r] : -1;
        ls_entry[t] = entry;
        if (PASS2) ls_gate[t] = (entry >= 0) ? gates[entry] : 0.f;
    }
    __syncthreads();

    float acc[8][8];
#pragma unroll
    for (int i = 0; i < 8; ++i)
#pragma unroll
        for (int j = 0; j < 8; ++j) acc[i][j] = 0.f;

    const int tx = t & 15, ty = t >> 4;
    const float* Wl = W + (size_t)e * KD * ND + col0;

    for (int k0 = 0; k0 < KD; k0 += 16) {
        // ---- stage A tile [128 rows][16 k] (transposed into As[k][m]) ----
#pragma unroll
        for (int i = 0; i < 2; ++i) {
            const int li = t + i * 256;       // 0..511
            const int row = li >> 2, kv = li & 3;
            const int entry = ls_entry[row];
            const int se = entry < 0 ? 0 : entry;
            const float* ap = PASS2 ? (A_src + (size_t)se * HDIM)
                                    : (A_src + (size_t)(se >> 1) * DDIM);
            const float4 av = *(const float4*)(ap + k0 + kv * 4);
            As[(kv * 4 + 0) * 132 + row] = av.x;
            As[(kv * 4 + 1) * 132 + row] = av.y;
            As[(kv * 4 + 2) * 132 + row] = av.z;
            As[(kv * 4 + 3) * 132 + row] = av.w;
        }
        // ---- stage B tile [16 k][128 cols] ----
#pragma unroll
        for (int i = 0; i < 2; ++i) {
            const int li = t + i * 256;
            const int kr = li >> 5, cv = li & 31;
            const float4 bv = *(const float4*)(Wl + (size_t)(k0 + kr) * ND + cv * 4);
            *(float4*)&Bs[kr * 128 + cv * 4] = bv;
        }
        __syncthreads();
#pragma unroll
        for (int kk = 0; kk < 16; ++kk) {
            const float4 a0 = *(const float4*)&As[kk * 132 + ty * 8];
            const float4 a1 = *(const float4*)&As[kk * 132 + ty * 8 + 4];
            const float4 b0 = *(const float4*)&Bs[kk * 128 + tx * 8];
            const float4 b1 = *(const float4*)&Bs[kk * 128 + tx * 8 + 4];
            const float a[8] = {a0.x, a0.y, a0.z, a0.w, a1.x, a1.y, a1.z, a1.w};
            const float b[8] = {b0.x, b0.y, b0.z, b0.w, b1.x, b1.y, b1.z, b1.w};
#pragma unroll
            for (int i = 0; i < 8; ++i)
#pragma unroll
                for (int j = 0; j < 8; ++j)
                    acc[i][j] = fmaf(a[i], b[j], acc[i][j]);
        }
        __syncthreads();
    }

    // ---- epilogue ----
#pragma unroll
    for (int i = 0; i < 8; ++i) {
        const int row = ty * 8 + i;
        const int entry = ls_entry[row];
        if (entry < 0) continue;
        if (!PASS2) {
            float* hr = outp + (size_t)entry * HDIM + col0 + tx * 8;
            float4 v0, v1;
            v0.x = fmaxf(acc[i][0] + bias[e * ND + col0 + tx * 8 + 0], 0.f);
            v0.y = fmaxf(acc[i][1] + bias[e * ND + col0 + tx * 8 + 1], 0.f);
            v0.z = fmaxf(acc[i][2] + bias[e * ND + col0 + tx * 8 + 2], 0.f);
            v0.w = fmaxf(acc[i][3] + bias[e * ND + col0 + tx * 8 + 3], 0.f);
            v1.x = fmaxf(acc[i][4] + bias[e * ND + col0 + tx * 8 + 4], 0.f);
            v1.y = fmaxf(acc[i][5] + bias[e * ND + col0 + tx * 8 + 5], 0.f);
            v1.z = fmaxf(acc[i][6] + bias[e * ND + col0 + tx * 8 + 6], 0.f);
            v1.w = fmaxf(acc[i][7] + bias[e * ND + col0 + tx * 8 + 7], 0.f);
            *(float4*)hr = v0;
            *(float4*)(hr + 4) = v1;
        } else {
            const float g = ls_gate[row];
            const int n = entry >> 1;
            float* yr = outp + (size_t)n * DDIM + col0 + tx * 8;
#pragma unroll
            for (int j = 0; j < 8; ++j) {
                const float v = (acc[i][j] + bias[e * ND + col0 + tx * 8 + j]) * g;
                atomicAdd(&yr[j], v);
            }
        }
    }
}

// ---------------------------------------------------------------------------
// Loss: CVLOSS=0 (skipped), SWITCHLOSS=0.01, ZLOSS=0.001.
// freqs[e] == counts[e] (top-k gate values are strictly positive).
// ---------------------------------------------------------------------------
__global__ void finalize_kernel(const int* __restrict__ counts,
                                const float* __restrict__ psum,
                                const float* __restrict__ zl_sum,
                                float* __restrict__ outp) {
    if (threadIdx.x == 0 && blockIdx.x == 0) {
        float S = 0.f;
        for (int e = 0; e < NEXP; ++e) S += psum[e];
        const float F = (float)(NTOK * TOPK);
        float sw = 0.f;
        for (int e = 0; e < NEXP; ++e)
            sw += (psum[e] / S) * ((float)counts[e] / F);
        sw *= (float)NEXP;
        const float zl = zl_sum[0] / (float)NTOK;
        outp[(size_t)NTOK * DDIM] = 0.01f * sw + 0.001f * zl;
    }
}

extern "C" void kernel_launch(void* const* d_in, const int* in_sizes, int n_in,
                              void* d_out, int out_size, void* d_ws, size_t ws_size,
                              hipStream_t stream) {
    (void)in_sizes; (void)n_in; (void)out_size; (void)ws_size;
    const float* x  = (const float*)d_in[0];
    const float* wg = (const float*)d_in[1];
    const float* w1 = (const float*)d_in[2];
    const float* b1 = (const float*)d_in[3];
    const float* w2 = (const float*)d_in[4];
    const float* b2 = (const float*)d_in[5];
    float* y = (float*)d_out;

    char* ws = (char*)d_ws;
    int*   counts = (int*)(ws + 0);
    float* psum   = (float*)(ws + WS_PSUM_OFF);
    float* zl     = (float*)(ws + WS_ZL_OFF);
    float* gates  = (float*)(ws + WS_GATES_OFF);
    int*   list   = (int*)(ws + WS_LIST_OFF);
    float* hbuf   = (float*)(ws + WS_HBUF_OFF);

    // zero accumulators and output (d_ws/d_out are poisoned before each call)
    hipMemsetAsync(ws, 0, 128, stream);
    hipMemsetAsync(d_out, 0, (size_t)NTOK * DDIM * sizeof(float), stream);

    gate_kernel<<<NTOK / 4, 256, 0, stream>>>(x, wg, counts, psum, zl, gates, list);

    ffn_gemm<DDIM, HDIM, false>
        <<<dim3(HDIM / 128, NTOK / 128, NEXP), 256, 0, stream>>>(
            x, w1, b1, counts, list, gates, hbuf);

    ffn_gemm<HDIM, DDIM, true>
        <<<dim3(DDIM / 128, NTOK / 128, NEXP), 256, 0, stream>>>(
            hbuf, w2, b2, counts, list, gates, y);

    finalize_kernel<<<1, 64, 0, stream>>>(counts, psum, zl, y);
}

// Round 2
// 434.623 us; speedup vs baseline: 2.2018x; 2.2018x over previous
//
#include <hip/hip_runtime.h>
#include <hip/hip_bf16.h>
#include <math.h>

// Problem constants (B=4, L=2048 -> N=8192 tokens)
#define NTOK 8192
#define DDIM 512
#define HDIM 1024
#define NEXP 8
#define TOPK 2

typedef __bf16 bf16;
typedef __attribute__((ext_vector_type(8))) __bf16 bf16x8;
typedef __attribute__((ext_vector_type(4))) float f32x4;

// ---------------- workspace layout (bytes) ----------------
#define WS_PSUM_OFF   32
#define WS_ZL_OFF     64
#define WS_GATES_OFF  128
#define WS_LIST_OFF   (WS_GATES_OFF + NTOK * TOPK * 4)            // 65664
#define WS_XB_OFF     327936                                      // 8192*512 bf16 = 8 MB
#define WS_W1T_OFF    (WS_XB_OFF + NTOK * DDIM * 2)               // [E][H][D] bf16 = 8 MB
#define WS_W2T_OFF    (WS_W1T_OFF + NEXP * DDIM * HDIM * 2)       // [E][D][H] bf16 = 8 MB
#define WS_HB_OFF     (WS_W2T_OFF + NEXP * DDIM * HDIM * 2)       // [16384][H] bf16 = 32 MB
// total ~56.3 MB (< proven-OK 67.4 MB from round 0)

#define GL2LDS(g, l) __builtin_amdgcn_global_load_lds( \
    (const __attribute__((address_space(1))) void*)(g), \
    (__attribute__((address_space(3))) void*)(l), 16, 0, 0)

// ---------------------------------------------------------------------------
// Gating: one wave per token (fp32 throughout — unchanged numerics).
// Also emits the bf16 copy of x used as GEMM A-operand.
// ---------------------------------------------------------------------------
__global__ __launch_bounds__(256)
void gate_kernel(const float* __restrict__ x, const float* __restrict__ wg,
                 int* __restrict__ counts, float* __restrict__ psum,
                 float* __restrict__ zl_sum, float* __restrict__ gates,
                 int* __restrict__ list, bf16* __restrict__ xb) {
    __shared__ float wls[NEXP * DDIM];   // 16 KB
    __shared__ float blk_psum[NEXP];
    __shared__ float blk_zl;
    const int t = threadIdx.x;

    for (int i = t; i < NEXP * DDIM / 4; i += 256)
        ((float4*)wls)[i] = ((const float4*)wg)[i];
    if (t < NEXP) blk_psum[t] = 0.f;
    if (t == 0) blk_zl = 0.f;
    __syncthreads();

    const int wave = t >> 6, lane = t & 63;
    const int n = blockIdx.x * 4 + wave;

    const float* xr = x + (size_t)n * DDIM;

    // bf16 copy of the token row (16B per lane)
    {
        const float4 v0 = ((const float4*)xr)[lane * 2];
        const float4 v1 = ((const float4*)xr)[lane * 2 + 1];
        bf16x8 bv;
        bv[0] = (bf16)v0.x; bv[1] = (bf16)v0.y; bv[2] = (bf16)v0.z; bv[3] = (bf16)v0.w;
        bv[4] = (bf16)v1.x; bv[5] = (bf16)v1.y; bv[6] = (bf16)v1.z; bv[7] = (bf16)v1.w;
        *(bf16x8*)(xb + (size_t)n * DDIM + lane * 8) = bv;
    }

    float acc[NEXP];
#pragma unroll
    for (int e = 0; e < NEXP; ++e) acc[e] = 0.f;
#pragma unroll
    for (int it = 0; it < DDIM / 64; ++it) {
        const float xv = xr[lane + 64 * it];
#pragma unroll
        for (int e = 0; e < NEXP; ++e)
            acc[e] = fmaf(xv, wls[e * DDIM + lane + 64 * it], acc[e]);
    }
#pragma unroll
    for (int e = 0; e < NEXP; ++e) {
#pragma unroll
        for (int off = 32; off > 0; off >>= 1)
            acc[e] += __shfl_xor(acc[e], off);
    }

    float m = acc[0];
#pragma unroll
    for (int e = 1; e < NEXP; ++e) m = fmaxf(m, acc[e]);
    float p[NEXP];
    float se = 0.f;
#pragma unroll
    for (int e = 0; e < NEXP; ++e) { p[e] = expf(acc[e] - m); se += p[e]; }
    const float lse = m + logf(se);
    const float inv = 1.f / se;
#pragma unroll
    for (int e = 0; e < NEXP; ++e) p[e] *= inv;

    int e0 = 0; float g0 = p[0];
#pragma unroll
    for (int e = 1; e < NEXP; ++e) if (p[e] > g0) { g0 = p[e]; e0 = e; }
    int e1 = -1; float g1 = -1.f;
#pragma unroll
    for (int e = 0; e < NEXP; ++e) if (e != e0 && p[e] > g1) { g1 = p[e]; e1 = e; }
    const float denom = g0 + g1 + 1e-6f;

    if (lane == 0) {
        gates[n * 2 + 0] = g0 / denom;
        gates[n * 2 + 1] = g1 / denom;
        const int p0 = atomicAdd(&counts[e0], 1);
        list[e0 * NTOK + p0] = n * 2 + 0;
        const int p1 = atomicAdd(&counts[e1], 1);
        list[e1 * NTOK + p1] = n * 2 + 1;
#pragma unroll
        for (int e = 0; e < NEXP; ++e) atomicAdd(&blk_psum[e], p[e]);
        atomicAdd(&blk_zl, lse * lse);
    }
    __syncthreads();
    if (t < NEXP) atomicAdd(&psum[t], blk_psum[t]);
    if (t == 0) atomicAdd(zl_sum, blk_zl);
}

// ---------------------------------------------------------------------------
// Weight convert + transpose: in [E][R][C] fp32 -> out [E][C][R] bf16.
// 32x32 LDS tiles, coalesced both sides.
// ---------------------------------------------------------------------------
template <int R, int C>
__global__ __launch_bounds__(256)
void transpose_cvt(const float* __restrict__ in, bf16* __restrict__ outp) {
    __shared__ float tile[32][33];
    const int e = blockIdx.z;
    const int x0 = blockIdx.x * 32;   // col block (input)
    const int y0 = blockIdx.y * 32;   // row block (input)
    const int tx = threadIdx.x & 31, ty = threadIdx.x >> 5;
    const float* ip = in + (size_t)e * R * C;
    bf16* op = outp + (size_t)e * R * C;
#pragma unroll
    for (int q = 0; q < 4; ++q)
        tile[ty + q * 8][tx] = ip[(size_t)(y0 + ty + q * 8) * C + x0 + tx];
    __syncthreads();
#pragma unroll
    for (int q = 0; q < 4; ++q)
        op[(size_t)(x0 + ty + q * 8) * R + y0 + tx] = (bf16)tile[tx][ty + q * 8];
}

// ---------------------------------------------------------------------------
// Gathered bf16 MFMA GEMM, 128x128 tile, BK=64, 4 waves (each 64x64 = 4x4
// frags of 16x16x32). A rows gathered per expert via per-lane global_load_lds
// source addresses; both A and B tiles are [row][K] in LDS with the T2 XOR
// chunk swizzle (inverse-swizzled source, swizzled ds_read; rule #21).
// PASS2=false: h[entry] = relu(xb[n] @ w1t[e]^T + b1[e])     KD=512  ND=1024
// PASS2=true : y[n]    += gate * (hb[entry] @ w2t[e]^T + b2) KD=1024 ND=512
// ---------------------------------------------------------------------------
template <int KD, int ND, bool PASS2>
__global__ __launch_bounds__(256)
void ffn_mfma(const bf16* __restrict__ A_src, const bf16* __restrict__ Wt,
              const float* __restrict__ bias, const int* __restrict__ counts,
              const int* __restrict__ list, const float* __restrict__ gates,
              float* __restrict__ y_out, bf16* __restrict__ h_out) {
    const int e = blockIdx.z;
    const int cnt = counts[e];
    const int row0 = blockIdx.y * 128;
    if (row0 >= cnt) return;
    const int col0 = blockIdx.x * 128;

    __shared__ __align__(16) short As[128 * 64];
    __shared__ __align__(16) short Bs[128 * 64];
    __shared__ int   ls_entry[128];
    __shared__ float ls_gate[128];

    const int t = threadIdx.x;
    const int lane = t & 63;
    const int w = t >> 6;

    if (t < 128) {
        const int r = row0 + t;
        const int entry = (r < cnt) ? list[e * NTOK + r] : -1;
        ls_entry[t] = entry;
        ls_gate[t] = (PASS2 && entry >= 0) ? gates[entry] : 0.f;
    }
    __syncthreads();

    // --- staging assignment (per-lane constants) ---
    // wave w, round q stages rows q*32 + w*8 + (lane>>3), chunk lane&7 of the
    // [128][64-bf16] tile (row = 8 chunks of 16B). Source chunk is XOR-swizzled
    // so that LDS[r][c] holds global chunk c^(r&7)  (r&7 == lane>>3 here).
    const int subrow = lane >> 3;
    const int swzoff = ((lane & 7) ^ subrow) * 16;   // bytes within 128B row window
    const char* Ab = (const char*)A_src;
    const char* Bb = (const char*)Wt;
    char* AsB = (char*)As;
    char* BsB = (char*)Bs;
    size_t a_row_byte[4], b_row_byte[4];
#pragma unroll
    for (int q = 0; q < 4; ++q) {
        const int r = q * 32 + w * 8 + subrow;
        const int entry = ls_entry[r];
        const int src = entry < 0 ? 0 : (PASS2 ? entry : (entry >> 1));
        a_row_byte[q] = (size_t)src * KD * 2;
        b_row_byte[q] = ((size_t)e * ND + col0 + r) * KD * 2;
    }
    const int lds_wbase = w * 8 * 128;   // wave-uniform LDS byte base

    f32x4 acc[4][4];
#pragma unroll
    for (int i = 0; i < 4; ++i)
#pragma unroll
        for (int j = 0; j < 4; ++j) acc[i][j] = (f32x4){0.f, 0.f, 0.f, 0.f};

    const int rowblk = (w >> 1) * 64;
    const int colblk = (w & 1) * 64;
    const int fr = lane & 15;     // fragment row (A) / col (B); fr&7 = row&7
    const int kg = lane >> 4;     // k-group 0..3

    for (int k0 = 0; k0 < KD; k0 += 64) {
        const size_t koff = (size_t)k0 * 2 + swzoff;
#pragma unroll
        for (int q = 0; q < 4; ++q) {
            GL2LDS(Ab + a_row_byte[q] + koff, AsB + lds_wbase + q * 32 * 128);
            GL2LDS(Bb + b_row_byte[q] + koff, BsB + lds_wbase + q * 32 * 128);
        }
        __syncthreads();
#pragma unroll
        for (int kk = 0; kk < 2; ++kk) {
            bf16x8 af[4], bg[4];
#pragma unroll
            for (int i = 0; i < 4; ++i) {
                const int ra = rowblk + i * 16 + fr;
                const int ca = (kk * 4 + kg) ^ (ra & 7);
                af[i] = *(const bf16x8*)(AsB + ra * 128 + ca * 16);
                const int rb = colblk + i * 16 + fr;
                const int cb = (kk * 4 + kg) ^ (rb & 7);
                bg[i] = *(const bf16x8*)(BsB + rb * 128 + cb * 16);
            }
#pragma unroll
            for (int i = 0; i < 4; ++i)
#pragma unroll
                for (int j = 0; j < 4; ++j)
                    acc[i][j] = __builtin_amdgcn_mfma_f32_16x16x32_bf16(
                        af[i], bg[j], acc[i][j], 0, 0, 0);
        }
        __syncthreads();
    }

    // --- epilogue --- C/D mapping: col = colblk + j*16 + fr, row = kg*4 + rg
    float bcol[4];
#pragma unroll
    for (int j = 0; j < 4; ++j)
        bcol[j] = bias[e * ND + col0 + colblk + j * 16 + fr];

#pragma unroll
    for (int i = 0; i < 4; ++i) {
#pragma unroll
        for (int rg = 0; rg < 4; ++rg) {
            const int r = rowblk + i * 16 + kg * 4 + rg;
            const int entry = ls_entry[r];
            if (entry < 0) continue;
            if (!PASS2) {
                bf16* hr = h_out + (size_t)entry * HDIM + col0 + colblk + fr;
#pragma unroll
                for (int j = 0; j < 4; ++j)
                    hr[j * 16] = (bf16)fmaxf(acc[i][j][rg] + bcol[j], 0.f);
            } else {
                const float g = ls_gate[r];
                float* yr = y_out + (size_t)(entry >> 1) * DDIM + col0 + colblk + fr;
#pragma unroll
                for (int j = 0; j < 4; ++j)
                    atomicAdd(&yr[j * 16], g * (acc[i][j][rg] + bcol[j]));
            }
        }
    }
}

// ---------------------------------------------------------------------------
__global__ void finalize_kernel(const int* __restrict__ counts,
                                const float* __restrict__ psum,
                                const float* __restrict__ zl_sum,
                                float* __restrict__ outp) {
    if (threadIdx.x == 0 && blockIdx.x == 0) {
        float S = 0.f;
        for (int e = 0; e < NEXP; ++e) S += psum[e];
        const float F = (float)(NTOK * TOPK);
        float sw = 0.f;
        for (int e = 0; e < NEXP; ++e)
            sw += (psum[e] / S) * ((float)counts[e] / F);
        sw *= (float)NEXP;
        const float zl = zl_sum[0] / (float)NTOK;
        outp[(size_t)NTOK * DDIM] = 0.01f * sw + 0.001f * zl;
    }
}

extern "C" void kernel_launch(void* const* d_in, const int* in_sizes, int n_in,
                              void* d_out, int out_size, void* d_ws, size_t ws_size,
                              hipStream_t stream) {
    (void)in_sizes; (void)n_in; (void)out_size; (void)ws_size;
    const float* x  = (const float*)d_in[0];
    const float* wg = (const float*)d_in[1];
    const float* w1 = (const float*)d_in[2];
    const float* b1 = (const float*)d_in[3];
    const float* w2 = (const float*)d_in[4];
    const float* b2 = (const float*)d_in[5];
    float* y = (float*)d_out;

    char* ws = (char*)d_ws;
    int*   counts = (int*)(ws + 0);
    float* psum   = (float*)(ws + WS_PSUM_OFF);
    float* zl     = (float*)(ws + WS_ZL_OFF);
    float* gates  = (float*)(ws + WS_GATES_OFF);
    int*   list   = (int*)(ws + WS_LIST_OFF);
    bf16*  xb     = (bf16*)(ws + WS_XB_OFF);
    bf16*  w1t    = (bf16*)(ws + WS_W1T_OFF);
    bf16*  w2t    = (bf16*)(ws + WS_W2T_OFF);
    bf16*  hb     = (bf16*)(ws + WS_HB_OFF);

    hipMemsetAsync(ws, 0, 128, stream);
    hipMemsetAsync(d_out, 0, (size_t)NTOK * DDIM * sizeof(float), stream);

    // weight convert+transpose: w1 [E][D][H] -> w1t [E][H][D]; w2 [E][H][D] -> w2t [E][D][H]
    transpose_cvt<DDIM, HDIM><<<dim3(HDIM / 32, DDIM / 32, NEXP), 256, 0, stream>>>(w1, w1t);
    transpose_cvt<HDIM, DDIM><<<dim3(DDIM / 32, HDIM / 32, NEXP), 256, 0, stream>>>(w2, w2t);

    gate_kernel<<<NTOK / 4, 256, 0, stream>>>(x, wg, counts, psum, zl, gates, list, xb);

    ffn_mfma<DDIM, HDIM, false>
        <<<dim3(HDIM / 128, NTOK / 128, NEXP), 256, 0, stream>>>(
            xb, w1t, b1, counts, list, gates, nullptr, hb);

    ffn_mfma<HDIM, DDIM, true>
        <<<dim3(DDIM / 128, NTOK / 128, NEXP), 256, 0, stream>>>(
            hb, w2t, b2, counts, list, gates, y, nullptr);

    finalize_kernel<<<1, 64, 0, stream>>>(counts, psum, zl, y);
}

// Round 3
// 261.214 us; speedup vs baseline: 3.6635x; 1.6639x over previous
//
#include <hip/hip_runtime.h>
#include <hip/hip_bf16.h>
#include <math.h>

// Problem constants (B=4, L=2048 -> N=8192 tokens)
#define NTOK 8192
#define DDIM 512
#define HDIM 1024
#define NEXP 8
#define TOPK 2
#define NBLK_GATE (NTOK / 4)   // 2048 gate blocks (4 tokens each)

typedef __bf16 bf16;
typedef __attribute__((ext_vector_type(8))) __bf16 bf16x8;
typedef __attribute__((ext_vector_type(4))) float f32x4;

// ---------------- workspace layout (bytes) ----------------
// counts: 8 counters padded to 256B stride each (atomic contention fix)
#define WS_PSUM_PART_OFF  4096                                    // [2048][8] f32 = 64 KB
#define WS_ZL_PART_OFF    (WS_PSUM_PART_OFF + NBLK_GATE * NEXP * 4)   // [2048] f32 = 8 KB
#define WS_GATES_OFF      (WS_ZL_PART_OFF + NBLK_GATE * 4)        // [NTOK*2] f32 = 64 KB
#define WS_LIST_OFF       (WS_GATES_OFF + NTOK * TOPK * 4)        // [8][8192] int = 256 KB
#define WS_XB_OFF         (WS_LIST_OFF + NEXP * NTOK * 4)         // 8192*512 bf16 = 8 MB
#define WS_W1T_OFF        (WS_XB_OFF + NTOK * DDIM * 2)           // [E][H][D] bf16 = 8 MB
#define WS_W2T_OFF        (WS_W1T_OFF + NEXP * DDIM * HDIM * 2)   // [E][D][H] bf16 = 8 MB
#define WS_HB_OFF         (WS_W2T_OFF + NEXP * DDIM * HDIM * 2)   // [16384][H] bf16 = 32 MB
// total ~59.1 MB (< proven-OK 67.4 MB from round 0)

#define GL2LDS(g, l) __builtin_amdgcn_global_load_lds( \
    (const __attribute__((address_space(1))) void*)(g), \
    (__attribute__((address_space(3))) void*)(l), 16, 0, 0)

// ---------------------------------------------------------------------------
// Gating: one wave per token (fp32 throughout). Emits bf16 copy of x.
// Atomic-contention-free: counts padded to 256B stride; psum/zl via plain
// per-block partial stores (reduced in finalize_kernel).
// ---------------------------------------------------------------------------
__global__ __launch_bounds__(256)
void gate_kernel(const float* __restrict__ x, const float* __restrict__ wg,
                 int* __restrict__ counts, float* __restrict__ psum_part,
                 float* __restrict__ zl_part, float* __restrict__ gates,
                 int* __restrict__ list, bf16* __restrict__ xb) {
    __shared__ float wls[NEXP * DDIM];   // 16 KB
    __shared__ float blk_psum[NEXP];
    __shared__ float blk_zl;
    const int t = threadIdx.x;

    for (int i = t; i < NEXP * DDIM / 4; i += 256)
        ((float4*)wls)[i] = ((const float4*)wg)[i];
    if (t < NEXP) blk_psum[t] = 0.f;
    if (t == 0) blk_zl = 0.f;
    __syncthreads();

    const int wave = t >> 6, lane = t & 63;
    const int n = blockIdx.x * 4 + wave;

    const float* xr = x + (size_t)n * DDIM;

    // bf16 copy of the token row (16B per lane)
    {
        const float4 v0 = ((const float4*)xr)[lane * 2];
        const float4 v1 = ((const float4*)xr)[lane * 2 + 1];
        bf16x8 bv;
        bv[0] = (bf16)v0.x; bv[1] = (bf16)v0.y; bv[2] = (bf16)v0.z; bv[3] = (bf16)v0.w;
        bv[4] = (bf16)v1.x; bv[5] = (bf16)v1.y; bv[6] = (bf16)v1.z; bv[7] = (bf16)v1.w;
        *(bf16x8*)(xb + (size_t)n * DDIM + lane * 8) = bv;
    }

    float acc[NEXP];
#pragma unroll
    for (int e = 0; e < NEXP; ++e) acc[e] = 0.f;
#pragma unroll
    for (int it = 0; it < DDIM / 64; ++it) {
        const float xv = xr[lane + 64 * it];
#pragma unroll
        for (int e = 0; e < NEXP; ++e)
            acc[e] = fmaf(xv, wls[e * DDIM + lane + 64 * it], acc[e]);
    }
#pragma unroll
    for (int e = 0; e < NEXP; ++e) {
#pragma unroll
        for (int off = 32; off > 0; off >>= 1)
            acc[e] += __shfl_xor(acc[e], off);
    }

    float m = acc[0];
#pragma unroll
    for (int e = 1; e < NEXP; ++e) m = fmaxf(m, acc[e]);
    float p[NEXP];
    float se = 0.f;
#pragma unroll
    for (int e = 0; e < NEXP; ++e) { p[e] = expf(acc[e] - m); se += p[e]; }
    const float lse = m + logf(se);
    const float inv = 1.f / se;
#pragma unroll
    for (int e = 0; e < NEXP; ++e) p[e] *= inv;

    int e0 = 0; float g0 = p[0];
#pragma unroll
    for (int e = 1; e < NEXP; ++e) if (p[e] > g0) { g0 = p[e]; e0 = e; }
    int e1 = -1; float g1 = -1.f;
#pragma unroll
    for (int e = 0; e < NEXP; ++e) if (e != e0 && p[e] > g1) { g1 = p[e]; e1 = e; }
    const float denom = g0 + g1 + 1e-6f;

    if (lane == 0) {
        gates[n * 2 + 0] = g0 / denom;
        gates[n * 2 + 1] = g1 / denom;
        const int p0 = atomicAdd(&counts[e0 * 64], 1);   // padded: own cache line
        list[e0 * NTOK + p0] = n * 2 + 0;
        const int p1 = atomicAdd(&counts[e1 * 64], 1);
        list[e1 * NTOK + p1] = n * 2 + 1;
#pragma unroll
        for (int e = 0; e < NEXP; ++e) atomicAdd(&blk_psum[e], p[e]);
        atomicAdd(&blk_zl, lse * lse);
    }
    __syncthreads();
    // plain per-block partial stores (no global atomics)
    if (t < NEXP) psum_part[blockIdx.x * NEXP + t] = blk_psum[t];
    if (t == 0) zl_part[blockIdx.x] = blk_zl;
}

// ---------------------------------------------------------------------------
// Weight convert + transpose: in [E][R][C] fp32 -> out [E][C][R] bf16.
// ---------------------------------------------------------------------------
template <int R, int C>
__global__ __launch_bounds__(256)
void transpose_cvt(const float* __restrict__ in, bf16* __restrict__ outp) {
    __shared__ float tile[32][33];
    const int e = blockIdx.z;
    const int x0 = blockIdx.x * 32;
    const int y0 = blockIdx.y * 32;
    const int tx = threadIdx.x & 31, ty = threadIdx.x >> 5;
    const float* ip = in + (size_t)e * R * C;
    bf16* op = outp + (size_t)e * R * C;
#pragma unroll
    for (int q = 0; q < 4; ++q)
        tile[ty + q * 8][tx] = ip[(size_t)(y0 + ty + q * 8) * C + x0 + tx];
    __syncthreads();
#pragma unroll
    for (int q = 0; q < 4; ++q)
        op[(size_t)(x0 + ty + q * 8) * R + y0 + tx] = (bf16)tile[tx][ty + q * 8];
}

// ---------------------------------------------------------------------------
// Gathered bf16 MFMA GEMM, 128x128 tile, BK=64, 4 waves (each 64x64 = 4x4
// frags of 16x16x32). A rows gathered per expert via per-lane global_load_lds
// source addresses; T2 XOR chunk swizzle (inverse-swizzled source, swizzled
// ds_read; rule #21).
// PASS2=false: h[entry] = relu(xb[n] @ w1t[e]^T + b1[e])     KD=512  ND=1024
// PASS2=true : y[n]    += gate * (hb[entry] @ w2t[e]^T + b2) KD=1024 ND=512
// ---------------------------------------------------------------------------
template <int KD, int ND, bool PASS2>
__global__ __launch_bounds__(256)
void ffn_mfma(const bf16* __restrict__ A_src, const bf16* __restrict__ Wt,
              const float* __restrict__ bias, const int* __restrict__ counts,
              const int* __restrict__ list, const float* __restrict__ gates,
              float* __restrict__ y_out, bf16* __restrict__ h_out) {
    const int e = blockIdx.z;
    const int cnt = counts[e * 64];
    const int row0 = blockIdx.y * 128;
    if (row0 >= cnt) return;
    const int col0 = blockIdx.x * 128;

    __shared__ __align__(16) short As[128 * 64];
    __shared__ __align__(16) short Bs[128 * 64];
    __shared__ int   ls_entry[128];
    __shared__ float ls_gate[128];

    const int t = threadIdx.x;
    const int lane = t & 63;
    const int w = t >> 6;

    if (t < 128) {
        const int r = row0 + t;
        const int entry = (r < cnt) ? list[e * NTOK + r] : -1;
        ls_entry[t] = entry;
        ls_gate[t] = (PASS2 && entry >= 0) ? gates[entry] : 0.f;
    }
    __syncthreads();

    const int subrow = lane >> 3;
    const int swzoff = ((lane & 7) ^ subrow) * 16;
    const char* Ab = (const char*)A_src;
    const char* Bb = (const char*)Wt;
    char* AsB = (char*)As;
    char* BsB = (char*)Bs;
    size_t a_row_byte[4], b_row_byte[4];
#pragma unroll
    for (int q = 0; q < 4; ++q) {
        const int r = q * 32 + w * 8 + subrow;
        const int entry = ls_entry[r];
        const int src = entry < 0 ? 0 : (PASS2 ? entry : (entry >> 1));
        a_row_byte[q] = (size_t)src * KD * 2;
        b_row_byte[q] = ((size_t)e * ND + col0 + r) * KD * 2;
    }
    const int lds_wbase = w * 8 * 128;

    f32x4 acc[4][4];
#pragma unroll
    for (int i = 0; i < 4; ++i)
#pragma unroll
        for (int j = 0; j < 4; ++j) acc[i][j] = (f32x4){0.f, 0.f, 0.f, 0.f};

    const int rowblk = (w >> 1) * 64;
    const int colblk = (w & 1) * 64;
    const int fr = lane & 15;
    const int kg = lane >> 4;

    for (int k0 = 0; k0 < KD; k0 += 64) {
        const size_t koff = (size_t)k0 * 2 + swzoff;
#pragma unroll
        for (int q = 0; q < 4; ++q) {
            GL2LDS(Ab + a_row_byte[q] + koff, AsB + lds_wbase + q * 32 * 128);
            GL2LDS(Bb + b_row_byte[q] + koff, BsB + lds_wbase + q * 32 * 128);
        }
        __syncthreads();
#pragma unroll
        for (int kk = 0; kk < 2; ++kk) {
            bf16x8 af[4], bg[4];
#pragma unroll
            for (int i = 0; i < 4; ++i) {
                const int ra = rowblk + i * 16 + fr;
                const int ca = (kk * 4 + kg) ^ (ra & 7);
                af[i] = *(const bf16x8*)(AsB + ra * 128 + ca * 16);
                const int rb = colblk + i * 16 + fr;
                const int cb = (kk * 4 + kg) ^ (rb & 7);
                bg[i] = *(const bf16x8*)(BsB + rb * 128 + cb * 16);
            }
#pragma unroll
            for (int i = 0; i < 4; ++i)
#pragma unroll
                for (int j = 0; j < 4; ++j)
                    acc[i][j] = __builtin_amdgcn_mfma_f32_16x16x32_bf16(
                        af[i], bg[j], acc[i][j], 0, 0, 0);
        }
        __syncthreads();
    }

    float bcol[4];
#pragma unroll
    for (int j = 0; j < 4; ++j)
        bcol[j] = bias[e * ND + col0 + colblk + j * 16 + fr];

#pragma unroll
    for (int i = 0; i < 4; ++i) {
#pragma unroll
        for (int rg = 0; rg < 4; ++rg) {
            const int r = rowblk + i * 16 + kg * 4 + rg;
            const int entry = ls_entry[r];
            if (entry < 0) continue;
            if (!PASS2) {
                bf16* hr = h_out + (size_t)entry * HDIM + col0 + colblk + fr;
#pragma unroll
                for (int j = 0; j < 4; ++j)
                    hr[j * 16] = (bf16)fmaxf(acc[i][j][rg] + bcol[j], 0.f);
            } else {
                const float g = ls_gate[r];
                float* yr = y_out + (size_t)(entry >> 1) * DDIM + col0 + colblk + fr;
#pragma unroll
                for (int j = 0; j < 4; ++j)
                    atomicAdd(&yr[j * 16], g * (acc[i][j][rg] + bcol[j]));
            }
        }
    }
}

// ---------------------------------------------------------------------------
// Reduce per-block partials + compute loss. 1 block.
// ---------------------------------------------------------------------------
__global__ __launch_bounds__(256)
void finalize_kernel(const int* __restrict__ counts,
                     const float* __restrict__ psum_part,
                     const float* __restrict__ zl_part,
                     float* __restrict__ outp) {
    __shared__ float sp[NEXP];
    __shared__ float sz;
    const int t = threadIdx.x;
    if (t < NEXP) sp[t] = 0.f;
    if (t == 0) sz = 0.f;
    __syncthreads();
    float pe[NEXP] = {0.f, 0.f, 0.f, 0.f, 0.f, 0.f, 0.f, 0.f};
    float z = 0.f;
    for (int b = t; b < NBLK_GATE; b += 256) {
#pragma unroll
        for (int e = 0; e < NEXP; ++e) pe[e] += psum_part[b * NEXP + e];
        z += zl_part[b];
    }
#pragma unroll
    for (int e = 0; e < NEXP; ++e) atomicAdd(&sp[e], pe[e]);
    atomicAdd(&sz, z);
    __syncthreads();
    if (t == 0) {
        float S = 0.f;
        for (int e = 0; e < NEXP; ++e) S += sp[e];
        const float F = (float)(NTOK * TOPK);
        float sw = 0.f;
        for (int e = 0; e < NEXP; ++e)
            sw += (sp[e] / S) * ((float)counts[e * 64] / F);
        sw *= (float)NEXP;
        const float zl = sz / (float)NTOK;
        outp[(size_t)NTOK * DDIM] = 0.01f * sw + 0.001f * zl;
    }
}

extern "C" void kernel_launch(void* const* d_in, const int* in_sizes, int n_in,
                              void* d_out, int out_size, void* d_ws, size_t ws_size,
                              hipStream_t stream) {
    (void)in_sizes; (void)n_in; (void)out_size; (void)ws_size;
    const float* x  = (const float*)d_in[0];
    const float* wg = (const float*)d_in[1];
    const float* w1 = (const float*)d_in[2];
    const float* b1 = (const float*)d_in[3];
    const float* w2 = (const float*)d_in[4];
    const float* b2 = (const float*)d_in[5];
    float* y = (float*)d_out;

    char* ws = (char*)d_ws;
    int*   counts    = (int*)(ws + 0);
    float* psum_part = (float*)(ws + WS_PSUM_PART_OFF);
    float* zl_part   = (float*)(ws + WS_ZL_PART_OFF);
    float* gates     = (float*)(ws + WS_GATES_OFF);
    int*   list      = (int*)(ws + WS_LIST_OFF);
    bf16*  xb        = (bf16*)(ws + WS_XB_OFF);
    bf16*  w1t       = (bf16*)(ws + WS_W1T_OFF);
    bf16*  w2t       = (bf16*)(ws + WS_W2T_OFF);
    bf16*  hb        = (bf16*)(ws + WS_HB_OFF);

    hipMemsetAsync(ws, 0, 4096, stream);   // zero padded counters
    hipMemsetAsync(d_out, 0, (size_t)NTOK * DDIM * sizeof(float), stream);

    transpose_cvt<DDIM, HDIM><<<dim3(HDIM / 32, DDIM / 32, NEXP), 256, 0, stream>>>(w1, w1t);
    transpose_cvt<HDIM, DDIM><<<dim3(DDIM / 32, HDIM / 32, NEXP), 256, 0, stream>>>(w2, w2t);

    gate_kernel<<<NBLK_GATE, 256, 0, stream>>>(x, wg, counts, psum_part, zl_part,
                                               gates, list, xb);

    ffn_mfma<DDIM, HDIM, false>
        <<<dim3(HDIM / 128, NTOK / 128, NEXP), 256, 0, stream>>>(
            xb, w1t, b1, counts, list, gates, nullptr, hb);

    ffn_mfma<HDIM, DDIM, true>
        <<<dim3(DDIM / 128, NTOK / 128, NEXP), 256, 0, stream>>>(
            hb, w2t, b2, counts, list, gates, y, nullptr);

    finalize_kernel<<<1, 256, 0, stream>>>(counts, psum_part, zl_part, y);
}

// Round 6
// 260.356 us; speedup vs baseline: 3.6756x; 1.0033x over previous
//
#include <hip/hip_runtime.h>
#include <hip/hip_bf16.h>
#include <math.h>

// Problem constants (B=4, L=2048 -> N=8192 tokens)
#define NTOK 8192
#define DDIM 512
#define HDIM 1024
#define NEXP 8
#define TOPK 2
#define NBLK_GATE (NTOK / 4)   // 2048 gate blocks (4 tokens each)

typedef __bf16 bf16;
typedef __attribute__((ext_vector_type(8))) __bf16 bf16x8;
typedef __attribute__((ext_vector_type(4))) float f32x4;

// ---------------- workspace layout (bytes) ----------------
#define WS_PSUM_PART_OFF  4096                                    // [2048][8] f32 = 64 KB
#define WS_ZL_PART_OFF    (WS_PSUM_PART_OFF + NBLK_GATE * NEXP * 4)   // [2048] f32 = 8 KB
#define WS_GATES_OFF      (WS_ZL_PART_OFF + NBLK_GATE * 4)        // [NTOK*2] f32 = 64 KB
#define WS_LIST_OFF       (WS_GATES_OFF + NTOK * TOPK * 4)        // [8][8192] int = 256 KB
#define WS_XB_OFF         (WS_LIST_OFF + NEXP * NTOK * 4)         // 8192*512 bf16 = 8 MB
#define WS_W1T_OFF        (WS_XB_OFF + NTOK * DDIM * 2)           // [E][H][D] bf16 = 8 MB
#define WS_W2T_OFF        (WS_W1T_OFF + NEXP * DDIM * HDIM * 2)   // [E][D][H] bf16 = 8 MB
#define WS_HB_OFF         (WS_W2T_OFF + NEXP * DDIM * HDIM * 2)   // [16384][H] bf16 = 32 MB

#define GL2LDS(g, l) __builtin_amdgcn_global_load_lds( \
    (const __attribute__((address_space(1))) void*)(g), \
    (__attribute__((address_space(3))) void*)(l), 16, 0, 0)

// ---------------------------------------------------------------------------
// Gating: one wave per token (fp32 throughout). Emits bf16 copy of x.
// counts padded to 256B stride; psum/zl via plain per-block partial stores.
// ---------------------------------------------------------------------------
__global__ __launch_bounds__(256)
void gate_kernel(const float* __restrict__ x, const float* __restrict__ wg,
                 int* __restrict__ counts, float* __restrict__ psum_part,
                 float* __restrict__ zl_part, float* __restrict__ gates,
                 int* __restrict__ list, bf16* __restrict__ xb) {
    __shared__ float wls[NEXP * DDIM];   // 16 KB
    __shared__ float blk_psum[NEXP];
    __shared__ float blk_zl;
    const int t = threadIdx.x;

    for (int i = t; i < NEXP * DDIM / 4; i += 256)
        ((float4*)wls)[i] = ((const float4*)wg)[i];
    if (t < NEXP) blk_psum[t] = 0.f;
    if (t == 0) blk_zl = 0.f;
    __syncthreads();

    const int wave = t >> 6, lane = t & 63;
    const int n = blockIdx.x * 4 + wave;

    const float* xr = x + (size_t)n * DDIM;

    {
        const float4 v0 = ((const float4*)xr)[lane * 2];
        const float4 v1 = ((const float4*)xr)[lane * 2 + 1];
        bf16x8 bv;
        bv[0] = (bf16)v0.x; bv[1] = (bf16)v0.y; bv[2] = (bf16)v0.z; bv[3] = (bf16)v0.w;
        bv[4] = (bf16)v1.x; bv[5] = (bf16)v1.y; bv[6] = (bf16)v1.z; bv[7] = (bf16)v1.w;
        *(bf16x8*)(xb + (size_t)n * DDIM + lane * 8) = bv;
    }

    float acc[NEXP];
#pragma unroll
    for (int e = 0; e < NEXP; ++e) acc[e] = 0.f;
#pragma unroll
    for (int it = 0; it < DDIM / 64; ++it) {
        const float xv = xr[lane + 64 * it];
#pragma unroll
        for (int e = 0; e < NEXP; ++e)
            acc[e] = fmaf(xv, wls[e * DDIM + lane + 64 * it], acc[e]);
    }
#pragma unroll
    for (int e = 0; e < NEXP; ++e) {
#pragma unroll
        for (int off = 32; off > 0; off >>= 1)
            acc[e] += __shfl_xor(acc[e], off);
    }

    float m = acc[0];
#pragma unroll
    for (int e = 1; e < NEXP; ++e) m = fmaxf(m, acc[e]);
    float p[NEXP];
    float se = 0.f;
#pragma unroll
    for (int e = 0; e < NEXP; ++e) { p[e] = expf(acc[e] - m); se += p[e]; }
    const float lse = m + logf(se);
    const float inv = 1.f / se;
#pragma unroll
    for (int e = 0; e < NEXP; ++e) p[e] *= inv;

    int e0 = 0; float g0 = p[0];
#pragma unroll
    for (int e = 1; e < NEXP; ++e) if (p[e] > g0) { g0 = p[e]; e0 = e; }
    int e1 = -1; float g1 = -1.f;
#pragma unroll
    for (int e = 0; e < NEXP; ++e) if (e != e0 && p[e] > g1) { g1 = p[e]; e1 = e; }
    const float denom = g0 + g1 + 1e-6f;

    if (lane == 0) {
        gates[n * 2 + 0] = g0 / denom;
        gates[n * 2 + 1] = g1 / denom;
        const int p0 = atomicAdd(&counts[e0 * 64], 1);   // padded: own cache line
        list[e0 * NTOK + p0] = n * 2 + 0;
        const int p1 = atomicAdd(&counts[e1 * 64], 1);
        list[e1 * NTOK + p1] = n * 2 + 1;
#pragma unroll
        for (int e = 0; e < NEXP; ++e) atomicAdd(&blk_psum[e], p[e]);
        atomicAdd(&blk_zl, lse * lse);
    }
    __syncthreads();
    if (t < NEXP) psum_part[blockIdx.x * NEXP + t] = blk_psum[t];
    if (t == 0) zl_part[blockIdx.x] = blk_zl;
}

// ---------------------------------------------------------------------------
// Weight convert + transpose: in [E][R][C] fp32 -> out [E][C][R] bf16.
// ---------------------------------------------------------------------------
template <int R, int C>
__global__ __launch_bounds__(256)
void transpose_cvt(const float* __restrict__ in, bf16* __restrict__ outp) {
    __shared__ float tile[32][33];
    const int e = blockIdx.z;
    const int x0 = blockIdx.x * 32;
    const int y0 = blockIdx.y * 32;
    const int tx = threadIdx.x & 31, ty = threadIdx.x >> 5;
    const float* ip = in + (size_t)e * R * C;
    bf16* op = outp + (size_t)e * R * C;
#pragma unroll
    for (int q = 0; q < 4; ++q)
        tile[ty + q * 8][tx] = ip[(size_t)(y0 + ty + q * 8) * C + x0 + tx];
    __syncthreads();
#pragma unroll
    for (int q = 0; q < 4; ++q)
        op[(size_t)(x0 + ty + q * 8) * R + y0 + tx] = (bf16)tile[tx][ty + q * 8];
}

// ---------------------------------------------------------------------------
// Gathered bf16 MFMA GEMM, 128x128 tile, BK=64, 4 waves, DOUBLE-BUFFERED
// 2-phase K-loop (T3 minimum recipe): STAGE(next) issued BEFORE COMPUTE(cur),
// one barrier per K-step -> prefetch latency hides under the MFMA cluster.
// T2 XOR chunk swizzle unchanged (inverse-swizzled source, swizzled ds_read).
// PASS2=false: h[entry] = relu(xb[n] @ w1t[e]^T + b1[e])     KD=512  ND=1024
// PASS2=true : y[n]    += gate * (hb[entry] @ w2t[e]^T + b2) KD=1024 ND=512
// ---------------------------------------------------------------------------
template <int KD, int ND, bool PASS2>
__global__ __launch_bounds__(256)
void ffn_mfma(const bf16* __restrict__ A_src, const bf16* __restrict__ Wt,
              const float* __restrict__ bias, const int* __restrict__ counts,
              const int* __restrict__ list, const float* __restrict__ gates,
              float* __restrict__ y_out, bf16* __restrict__ h_out) {
    const int e = blockIdx.z;
    const int cnt = counts[e * 64];
    const int row0 = blockIdx.y * 128;
    if (row0 >= cnt) return;
    const int col0 = blockIdx.x * 128;

    // 2 buffers x [128 rows][64 bf16] per operand = 64 KB total
    __shared__ __align__(16) short As[2][128 * 64];
    __shared__ __align__(16) short Bs[2][128 * 64];
    __shared__ int   ls_entry[128];
    __shared__ float ls_gate[128];

    const int t = threadIdx.x;
    const int lane = t & 63;
    const int w = t >> 6;

    if (t < 128) {
        const int r = row0 + t;
        const int entry = (r < cnt) ? list[e * NTOK + r] : -1;
        ls_entry[t] = entry;
        ls_gate[t] = (PASS2 && entry >= 0) ? gates[entry] : 0.f;
    }
    __syncthreads();

    const int subrow = lane >> 3;
    const int swzoff = ((lane & 7) ^ subrow) * 16;
    const char* Ab = (const char*)A_src;
    const char* Bb = (const char*)Wt;
    size_t a_row_byte[4], b_row_byte[4];
#pragma unroll
    for (int q = 0; q < 4; ++q) {
        const int r = q * 32 + w * 8 + subrow;
        const int entry = ls_entry[r];
        const int src = entry < 0 ? 0 : (PASS2 ? entry : (entry >> 1));
        a_row_byte[q] = (size_t)src * KD * 2;
        b_row_byte[q] = ((size_t)e * ND + col0 + r) * KD * 2;
    }
    const int lds_wbase = w * 8 * 128;   // wave-uniform byte base within a buffer

    f32x4 acc[4][4];
#pragma unroll
    for (int i = 0; i < 4; ++i)
#pragma unroll
        for (int j = 0; j < 4; ++j) acc[i][j] = (f32x4){0.f, 0.f, 0.f, 0.f};

    const int rowblk = (w >> 1) * 64;
    const int colblk = (w & 1) * 64;
    const int fr = lane & 15;
    const int kg = lane >> 4;

    auto STAGE = [&](int buf, int k0) {
        const size_t koff = (size_t)k0 * 2 + swzoff;
        char* ab = (char*)As + buf * 16384 + lds_wbase;
        char* bb = (char*)Bs + buf * 16384 + lds_wbase;
#pragma unroll
        for (int q = 0; q < 4; ++q) {
            GL2LDS(Ab + a_row_byte[q] + koff, ab + q * 32 * 128);
            GL2LDS(Bb + b_row_byte[q] + koff, bb + q * 32 * 128);
        }
    };

    auto COMPUTE = [&](int buf) {
        const char* AsB = (const char*)As + buf * 16384;
        const char* BsB = (const char*)Bs + buf * 16384;
#pragma unroll
        for (int kk = 0; kk < 2; ++kk) {
            bf16x8 af[4], bg[4];
#pragma unroll
            for (int i = 0; i < 4; ++i) {
                const int ra = rowblk + i * 16 + fr;
                const int ca = (kk * 4 + kg) ^ (ra & 7);
                af[i] = *(const bf16x8*)(AsB + ra * 128 + ca * 16);
                const int rb = colblk + i * 16 + fr;
                const int cb = (kk * 4 + kg) ^ (rb & 7);
                bg[i] = *(const bf16x8*)(BsB + rb * 128 + cb * 16);
            }
#pragma unroll
            for (int i = 0; i < 4; ++i)
#pragma unroll
                for (int j = 0; j < 4; ++j)
                    acc[i][j] = __builtin_amdgcn_mfma_f32_16x16x32_bf16(
                        af[i], bg[j], acc[i][j], 0, 0, 0);
        }
    };

    constexpr int NT = KD / 64;
    STAGE(0, 0);
    __syncthreads();                       // auto vmcnt(0) drain: buf0 ready
    for (int kt = 0; kt < NT - 1; ++kt) {
        STAGE((kt + 1) & 1, (kt + 1) * 64);  // prefetch next tile
        COMPUTE(kt & 1);                     // MFMA on current tile
        __syncthreads();                     // drain prefetch + reads done
    }
    COMPUTE((NT - 1) & 1);

    // --- epilogue --- C/D mapping: col = colblk + j*16 + fr, row = kg*4 + rg
    float bcol[4];
#pragma unroll
    for (int j = 0; j < 4; ++j)
        bcol[j] = bias[e * ND + col0 + colblk + j * 16 + fr];

#pragma unroll
    for (int i = 0; i < 4; ++i) {
#pragma unroll
        for (int rg = 0; rg < 4; ++rg) {
            const int r = rowblk + i * 16 + kg * 4 + rg;
            const int entry = ls_entry[r];
            if (entry < 0) continue;
            if (!PASS2) {
                bf16* hr = h_out + (size_t)entry * HDIM + col0 + colblk + fr;
#pragma unroll
                for (int j = 0; j < 4; ++j)
                    hr[j * 16] = (bf16)fmaxf(acc[i][j][rg] + bcol[j], 0.f);
            } else {
                const float g = ls_gate[r];
                float* yr = y_out + (size_t)(entry >> 1) * DDIM + col0 + colblk + fr;
#pragma unroll
                for (int j = 0; j < 4; ++j)
                    atomicAdd(&yr[j * 16], g * (acc[i][j][rg] + bcol[j]));
            }
        }
    }
}

// ---------------------------------------------------------------------------
// Reduce per-block partials + compute loss. 1 block.
// ---------------------------------------------------------------------------
__global__ __launch_bounds__(256)
void finalize_kernel(const int* __restrict__ counts,
                     const float* __restrict__ psum_part,
                     const float* __restrict__ zl_part,
                     float* __restrict__ outp) {
    __shared__ float sp[NEXP];
    __shared__ float sz;
    const int t = threadIdx.x;
    if (t < NEXP) sp[t] = 0.f;
    if (t == 0) sz = 0.f;
    __syncthreads();
    float pe[NEXP] = {0.f, 0.f, 0.f, 0.f, 0.f, 0.f, 0.f, 0.f};
    float z = 0.f;
    for (int b = t; b < NBLK_GATE; b += 256) {
#pragma unroll
        for (int e = 0; e < NEXP; ++e) pe[e] += psum_part[b * NEXP + e];
        z += zl_part[b];
    }
#pragma unroll
    for (int e = 0; e < NEXP; ++e) atomicAdd(&sp[e], pe[e]);
    atomicAdd(&sz, z);
    __syncthreads();
    if (t == 0) {
        float S = 0.f;
        for (int e = 0; e < NEXP; ++e) S += sp[e];
        const float F = (float)(NTOK * TOPK);
        float sw = 0.f;
        for (int e = 0; e < NEXP; ++e)
            sw += (sp[e] / S) * ((float)counts[e * 64] / F);
        sw *= (float)NEXP;
        const float zl = sz / (float)NTOK;
        outp[(size_t)NTOK * DDIM] = 0.01f * sw + 0.001f * zl;
    }
}

extern "C" void kernel_launch(void* const* d_in, const int* in_sizes, int n_in,
                              void* d_out, int out_size, void* d_ws, size_t ws_size,
                              hipStream_t stream) {
    (void)in_sizes; (void)n_in; (void)out_size; (void)ws_size;
    const float* x  = (const float*)d_in[0];
    const float* wg = (const float*)d_in[1];
    const float* w1 = (const float*)d_in[2];
    const float* b1 = (const float*)d_in[3];
    const float* w2 = (const float*)d_in[4];
    const float* b2 = (const float*)d_in[5];
    float* y = (float*)d_out;

    char* ws = (char*)d_ws;
    int*   counts    = (int*)(ws + 0);
    float* psum_part = (float*)(ws + WS_PSUM_PART_OFF);
    float* zl_part   = (float*)(ws + WS_ZL_PART_OFF);
    float* gates     = (float*)(ws + WS_GATES_OFF);
    int*   list      = (int*)(ws + WS_LIST_OFF);
    bf16*  xb        = (bf16*)(ws + WS_XB_OFF);
    bf16*  w1t       = (bf16*)(ws + WS_W1T_OFF);
    bf16*  w2t       = (bf16*)(ws + WS_W2T_OFF);
    bf16*  hb        = (bf16*)(ws + WS_HB_OFF);

    hipMemsetAsync(ws, 0, 4096, stream);
    hipMemsetAsync(d_out, 0, (size_t)NTOK * DDIM * sizeof(float), stream);

    transpose_cvt<DDIM, HDIM><<<dim3(HDIM / 32, DDIM / 32, NEXP), 256, 0, stream>>>(w1, w1t);
    transpose_cvt<HDIM, DDIM><<<dim3(DDIM / 32, HDIM / 32, NEXP), 256, 0, stream>>>(w2, w2t);

    gate_kernel<<<NBLK_GATE, 256, 0, stream>>>(x, wg, counts, psum_part, zl_part,
                                               gates, list, xb);

    ffn_mfma<DDIM, HDIM, false>
        <<<dim3(HDIM / 128, NTOK / 128, NEXP), 256, 0, stream>>>(
            xb, w1t, b1, counts, list, gates, nullptr, hb);

    ffn_mfma<HDIM, DDIM, true>
        <<<dim3(DDIM / 128, NTOK / 128, NEXP), 256, 0, stream>>>(
            hb, w2t, b2, counts, list, gates, y, nullptr);

    finalize_kernel<<<1, 256, 0, stream>>>(counts, psum_part, zl_part, y);
}